// Round 8
// baseline (32.289 us; speedup 1.0000x reference)
//
#include <hip/hip_runtime.h>

// OCDM modulator, 8 rows (2×4-row groups) per wave iteration.
// Identical to the round-3 kernel (best: 29.3 us) EXCEPT the input loads
// are nontemporal (evict-first hint) — the 67 MB input stream is touch-once
// and only pollutes L2 for the 84 MB write stream. Stores are NORMAL
// (nt stores caused post-timing divergence in round 6 — disqualified).
// nt builtins require clang ext_vector_type pointers, not HIP_vector_type.
//
// Row of N=64: chirped = sym * exp(i*pi*k^2/64) ; td = unnormalized IDFT * 1/8
// out row = [td[48:64], td[0:64]] as 80 (re,im) float pairs.
//
// Decomposition k = 4j+q (j=0..15 lane-in-group, q in-lane):
//   Y_q[m]   = 16-pt inverse DFT across lanes (radix-2 DIF, m = bitrev4(j))
//   Z_q      = Y_q[m] * e^{+2pi i m q/64}
//   X[m+16s] = sum_q i^{q s} Z_q      (in-lane radix-4)
// Lane l (j=l&15, g=l>>4) handles row g of each 4-row group.
// Both groups' outputs staged in a 640-float2/wave LDS stream laid out
// exactly as the output, then drained with 5 float4 stores per lane.

typedef float f4 __attribute__((ext_vector_type(4)));

__global__ __launch_bounds__(256) void ocdm_kernel(
    const f4* __restrict__ re4,
    const f4* __restrict__ im4,
    float4* __restrict__ out4,
    int n_pairs)                        // n_rows / 8
{
    const int l = threadIdx.x & 63;
    const int w = threadIdx.x >> 6;
    const int g = l >> 4;               // row within 4-row group
    const int j = l & 15;               // lane within 16-pt DFT
    const int wave_global = blockIdx.x * (blockDim.x >> 6) + w;
    const int wave_stride = gridDim.x * (blockDim.x >> 6);

    __shared__ alignas(16) float2 lds[4][640];

    // chirp[k]/8, k = 4j+q  (exp(i*pi*k^2/64), k^2 mod 128)
    float ckr[4], cki[4];
#pragma unroll
    for (int q = 0; q < 4; ++q) {
        int k = 4 * j + q;
        float f = (float)((k * k) & 127) * (1.0f / 64.0f);
        ckr[q] = 0.125f * cospif(f);
        cki[q] = 0.125f * sinpif(f);
    }

    // 16-pt inverse DIF stage constants (depend only on j)
    const int D[4] = {8, 4, 2, 1};
    float twr[4], twi[4], sg[4];
#pragma unroll
    for (int s = 0; s < 4; ++s) {
        int d = D[s];
        int jj = j & (d - 1);
        bool up = (j & d) != 0;
        float f = (float)jj / (float)d;
        twr[s] = up ? cospif(f) : 1.0f;
        twi[s] = up ? sinpif(f) : 0.0f;
        sg[s]  = up ? -1.0f : 1.0f;
    }

    const int m = (int)(__brev((unsigned)j) >> 28);   // bitrev4(j)

    // inter-stage twiddles e^{+2pi i m q / 64}, q = 1..3
    float tqr[3], tqi[3];
#pragma unroll
    for (int q = 1; q <= 3; ++q) {
        float f = (float)(m * q) * (1.0f / 32.0f);
        tqr[q - 1] = cospif(f);
        tqi[q - 1] = sinpif(f);
    }

    const int wbase = g * 80;

    // one 4-row group: chirp * IDFT64, permuted store into lds[w][base+...]
    auto fft_group = [&](f4 vr, f4 vi, int base) {
        float xr[4], xi[4];
        {
            const float rr[4] = {vr.x, vr.y, vr.z, vr.w};
            const float ii[4] = {vi.x, vi.y, vi.z, vi.w};
#pragma unroll
            for (int q = 0; q < 4; ++q) {
                xr[q] = rr[q] * ckr[q] - ii[q] * cki[q];
                xi[q] = fmaf(rr[q], cki[q], ii[q] * ckr[q]);
            }
        }

        // 16-pt inverse DFT across lanes — 4 independent sequences (ILP)
#pragma unroll
        for (int s = 0; s < 4; ++s) {
#pragma unroll
            for (int q = 0; q < 4; ++q) {
                float pr = __shfl_xor(xr[q], D[s]);
                float pi = __shfl_xor(xi[q], D[s]);
                float ar = fmaf(sg[s], xr[q], pr);   // lower: x+p, upper: p-x
                float ai = fmaf(sg[s], xi[q], pi);
                xr[q] = ar * twr[s] - ai * twi[s];
                xi[q] = fmaf(ar, twi[s], ai * twr[s]);
            }
        }

        // twiddle by e^{+2pi i m q/64}
#pragma unroll
        for (int q = 1; q <= 3; ++q) {
            float ar = xr[q] * tqr[q - 1] - xi[q] * tqi[q - 1];
            float ai = fmaf(xr[q], tqi[q - 1], xi[q] * tqr[q - 1]);
            xr[q] = ar; xi[q] = ai;
        }

        // in-lane radix-4 (inverse): X[m+16s]
        float Ar = xr[0] + xr[2], Ai = xi[0] + xi[2];
        float Br = xr[0] - xr[2], Bi = xi[0] - xi[2];
        float Cr = xr[1] + xr[3], Ci = xi[1] + xi[3];
        float Dr = xr[1] - xr[3], Di = xi[1] - xi[3];
        float2 X0 = make_float2(Ar + Cr, Ai + Ci);    // n=m
        float2 X1 = make_float2(Br - Di, Bi + Dr);    // n=m+16
        float2 X2 = make_float2(Ar - Cr, Ai - Ci);    // n=m+32
        float2 X3 = make_float2(Br + Di, Bi - Dr);    // n=m+48

        // out slot within 4-row chunk for td[n]: (n+16)&63, plus n+16 if n>=48
        const int b = base + wbase;
        lds[w][b + m + 16] = X0;
        lds[w][b + m + 32] = X1;
        lds[w][b + m + 48] = X2;
        lds[w][b + m]      = X3;
        lds[w][b + m + 64] = X3;                      // cyclic prefix dup
    };

    for (int p = wave_global; p < n_pairs; p += wave_stride) {
        const int rb = p * 2;                         // 4-row group index
        // issue all four 16B loads up front (nontemporal: touch-once stream);
        // group-1's latency hides under group-0's FFT
        f4 vr0 = __builtin_nontemporal_load(re4 + rb * 64 + l);
        f4 vi0 = __builtin_nontemporal_load(im4 + rb * 64 + l);
        f4 vr1 = __builtin_nontemporal_load(re4 + (rb + 1) * 64 + l);
        f4 vi1 = __builtin_nontemporal_load(im4 + (rb + 1) * 64 + l);

        fft_group(vr0, vi0, 0);
        fft_group(vr1, vi1, 320);

        asm volatile("s_waitcnt lgkmcnt(0)" ::: "memory");

        const float4* lsrc = (const float4*)&lds[w][0];
        const long ob = (long)p * 320;
#pragma unroll
        for (int i = 0; i < 5; ++i)
            out4[ob + i * 64 + l] = lsrc[i * 64 + l];
        // next iteration's ds_writes are ordered after these ds_reads by
        // in-order per-wave DS execution
    }
}

extern "C" void kernel_launch(void* const* d_in, const int* in_sizes, int n_in,
                              void* d_out, int out_size, void* d_ws, size_t ws_size,
                              hipStream_t stream) {
    const f4* re4 = (const f4*)d_in[0];
    const f4* im4 = (const f4*)d_in[1];
    float4* out4 = (float4*)d_out;

    const int n_rows = in_sizes[0] / 64;     // 131072
    const int n_pairs = n_rows / 8;          // 16384

    int blocks = (n_pairs + 3) / 4;
    if (blocks > 2048) blocks = 2048;        // 8192 waves, 2 pairs each
    ocdm_kernel<<<blocks, 256, 0, stream>>>(re4, im4, out4, n_pairs);
}

// Round 9
// 29.752 us; speedup vs baseline: 1.0853x; 1.0853x over previous
//
#include <hip/hip_runtime.h>

// OCDM modulator — FINAL (round-3 structure, the best of 8 A/B'd variants).
// 8 rows (2×4-row groups) per wave iteration; LDS-staged permuted output;
// plain (cached) loads and stores — nt hints and pipeline restructures all
// measured neutral-to-worse (R4/R5/R8) or incorrect (R6 nt-stores).
//
// Row of N=64: chirped = sym * exp(i*pi*k^2/64) ; td = unnormalized IDFT * 1/8
// out row = [td[48:64], td[0:64]] as 80 (re,im) float pairs.
//
// Decomposition k = 4j+q (j=0..15 lane-in-group, q in-lane):
//   Y_q[m]   = 16-pt inverse DFT across lanes (radix-2 DIF, m = bitrev4(j))
//   Z_q      = Y_q[m] * e^{+2pi i m q/64}
//   X[m+16s] = sum_q i^{q s} Z_q      (in-lane radix-4)
// Lane l (j=l&15, g=l>>4) handles row g of each 4-row group.
// Both groups' outputs staged in a 640-float2/wave LDS stream laid out
// exactly as the output, then drained with 5 float4 stores per lane.
//
// 151 MB touch-once traffic @ ~5.15 TB/s effective = 82% of the measured
// float4-copy ceiling (~90%+ net of launch overhead) — memory roofline.

__global__ __launch_bounds__(256) void ocdm_kernel(
    const float4* __restrict__ re4,
    const float4* __restrict__ im4,
    float4* __restrict__ out4,
    int n_pairs)                        // n_rows / 8
{
    const int l = threadIdx.x & 63;
    const int w = threadIdx.x >> 6;
    const int g = l >> 4;               // row within 4-row group
    const int j = l & 15;               // lane within 16-pt DFT
    const int wave_global = blockIdx.x * (blockDim.x >> 6) + w;
    const int wave_stride = gridDim.x * (blockDim.x >> 6);

    __shared__ alignas(16) float2 lds[4][640];

    // chirp[k]/8, k = 4j+q  (exp(i*pi*k^2/64), k^2 mod 128)
    float ckr[4], cki[4];
#pragma unroll
    for (int q = 0; q < 4; ++q) {
        int k = 4 * j + q;
        float f = (float)((k * k) & 127) * (1.0f / 64.0f);
        ckr[q] = 0.125f * cospif(f);
        cki[q] = 0.125f * sinpif(f);
    }

    // 16-pt inverse DIF stage constants (depend only on j)
    const int D[4] = {8, 4, 2, 1};
    float twr[4], twi[4], sg[4];
#pragma unroll
    for (int s = 0; s < 4; ++s) {
        int d = D[s];
        int jj = j & (d - 1);
        bool up = (j & d) != 0;
        float f = (float)jj / (float)d;
        twr[s] = up ? cospif(f) : 1.0f;
        twi[s] = up ? sinpif(f) : 0.0f;
        sg[s]  = up ? -1.0f : 1.0f;
    }

    const int m = (int)(__brev((unsigned)j) >> 28);   // bitrev4(j)

    // inter-stage twiddles e^{+2pi i m q / 64}, q = 1..3
    float tqr[3], tqi[3];
#pragma unroll
    for (int q = 1; q <= 3; ++q) {
        float f = (float)(m * q) * (1.0f / 32.0f);
        tqr[q - 1] = cospif(f);
        tqi[q - 1] = sinpif(f);
    }

    const int wbase = g * 80;

    // one 4-row group: chirp * IDFT64, permuted store into lds[w][base+...]
    auto fft_group = [&](float4 vr, float4 vi, int base) {
        float xr[4], xi[4];
        {
            const float rr[4] = {vr.x, vr.y, vr.z, vr.w};
            const float ii[4] = {vi.x, vi.y, vi.z, vi.w};
#pragma unroll
            for (int q = 0; q < 4; ++q) {
                xr[q] = rr[q] * ckr[q] - ii[q] * cki[q];
                xi[q] = fmaf(rr[q], cki[q], ii[q] * ckr[q]);
            }
        }

        // 16-pt inverse DFT across lanes — 4 independent sequences (ILP)
#pragma unroll
        for (int s = 0; s < 4; ++s) {
#pragma unroll
            for (int q = 0; q < 4; ++q) {
                float pr = __shfl_xor(xr[q], D[s]);
                float pi = __shfl_xor(xi[q], D[s]);
                float ar = fmaf(sg[s], xr[q], pr);   // lower: x+p, upper: p-x
                float ai = fmaf(sg[s], xi[q], pi);
                xr[q] = ar * twr[s] - ai * twi[s];
                xi[q] = fmaf(ar, twi[s], ai * twr[s]);
            }
        }

        // twiddle by e^{+2pi i m q/64}
#pragma unroll
        for (int q = 1; q <= 3; ++q) {
            float ar = xr[q] * tqr[q - 1] - xi[q] * tqi[q - 1];
            float ai = fmaf(xr[q], tqi[q - 1], xi[q] * tqr[q - 1]);
            xr[q] = ar; xi[q] = ai;
        }

        // in-lane radix-4 (inverse): X[m+16s]
        float Ar = xr[0] + xr[2], Ai = xi[0] + xi[2];
        float Br = xr[0] - xr[2], Bi = xi[0] - xi[2];
        float Cr = xr[1] + xr[3], Ci = xi[1] + xi[3];
        float Dr = xr[1] - xr[3], Di = xi[1] - xi[3];
        float2 X0 = make_float2(Ar + Cr, Ai + Ci);    // n=m
        float2 X1 = make_float2(Br - Di, Bi + Dr);    // n=m+16
        float2 X2 = make_float2(Ar - Cr, Ai - Ci);    // n=m+32
        float2 X3 = make_float2(Br + Di, Bi - Dr);    // n=m+48

        // out slot within 4-row chunk for td[n]: (n+16)&63, plus n+16 if n>=48
        const int b = base + wbase;
        lds[w][b + m + 16] = X0;
        lds[w][b + m + 32] = X1;
        lds[w][b + m + 48] = X2;
        lds[w][b + m]      = X3;
        lds[w][b + m + 64] = X3;                      // cyclic prefix dup
    };

    for (int p = wave_global; p < n_pairs; p += wave_stride) {
        const int rb = p * 2;                         // 4-row group index
        // issue all four 16B loads up front; group-1's latency hides
        // under group-0's FFT
        float4 vr0 = re4[rb * 64 + l];
        float4 vi0 = im4[rb * 64 + l];
        float4 vr1 = re4[(rb + 1) * 64 + l];
        float4 vi1 = im4[(rb + 1) * 64 + l];

        fft_group(vr0, vi0, 0);
        fft_group(vr1, vi1, 320);

        asm volatile("s_waitcnt lgkmcnt(0)" ::: "memory");

        const float4* lsrc = (const float4*)&lds[w][0];
        const long ob = (long)p * 320;
#pragma unroll
        for (int i = 0; i < 5; ++i)
            out4[ob + i * 64 + l] = lsrc[i * 64 + l];
        // next iteration's ds_writes are ordered after these ds_reads by
        // in-order per-wave DS execution
    }
}

extern "C" void kernel_launch(void* const* d_in, const int* in_sizes, int n_in,
                              void* d_out, int out_size, void* d_ws, size_t ws_size,
                              hipStream_t stream) {
    const float4* re4 = (const float4*)d_in[0];
    const float4* im4 = (const float4*)d_in[1];
    float4* out4 = (float4*)d_out;

    const int n_rows = in_sizes[0] / 64;     // 131072
    const int n_pairs = n_rows / 8;          // 16384

    int blocks = (n_pairs + 3) / 4;
    if (blocks > 2048) blocks = 2048;        // 8192 waves, 2 pairs each
    ocdm_kernel<<<blocks, 256, 0, stream>>>(re4, im4, out4, n_pairs);
}